// Round 10
// baseline (313.091 us; speedup 1.0000x reference)
//
#include <hip/hip_runtime.h>
#include <hip/hip_bf16.h>

// DBRX MoE experts forward, MI355X gfx950.
// T=2048, H=1024, F=2048, E=8, K=2. f32 storage in/out; bf16 MFMA compute.
// Round 16: r15 base (311.9us proven) + ONE zero-resource glu change:
// B(t+1) f32 weight loads issue BEFORE the barrier, raw s_barrier +
// counted "s_waitcnt vmcnt(4)" (outstanding FIFO at that point is exactly
// [A(t) async, B(t+1) x4] -> pops A(t), B rides across the barrier).
// Same single B register set (loads overwrite the just-consumed regs: no
// r14 VGPR growth), same LDS, one sched_barrier(0) pin so the loads can't
// hoist above the cvt and spike live ranges. Cover for the compulsory-HBM
// weight loads grows by the barrier-sync time. Tail drains vmcnt(0).
// Also: gather_x grid 48x8 -> 48x16. Everything else identical to r15.

#define T_ 2048
#define H_ 1024
#define F_ 2048
#define E_ 8

#define SCAP 768                  // per-expert slot capacity (multiple of 128)
#define NSLOT (E_ * SCAP)         // 6144
#define MAXT2 (NSLOT / 128)       // 48 max 128-slot tiles

typedef unsigned short u16;
typedef short s8v __attribute__((ext_vector_type(8)));
typedef float f4v __attribute__((ext_vector_type(4)));
typedef unsigned short u16x4 __attribute__((ext_vector_type(4)));

__device__ __forceinline__ u16 f2bf(float f) {
    union { float f; unsigned u; } v; v.f = f;
    unsigned r = v.u + 0x7FFF + ((v.u >> 16) & 1);   // RNE
    return (u16)(r >> 16);
}
__device__ __forceinline__ unsigned pkbf(float a, float b) {
    __hip_bfloat162 h = __float22bfloat162_rn(make_float2(a, b));
    union { __hip_bfloat162 h; unsigned u; } c; c.h = h; return c.u;
}
__device__ __forceinline__ int4 cvt8(const float4 a, const float4 b) {
    int4 r; r.x = (int)pkbf(a.x, a.y); r.y = (int)pkbf(a.z, a.w);
    r.z = (int)pkbf(b.x, b.y); r.w = (int)pkbf(b.z, b.w); return r;
}
// async 16B/lane global->LDS; LDS dest stays LINEAR (wave base + lane*16).
// Swizzle applied on the GLOBAL source chunk (chunk ^ ((row>>1)&3)) and
// mirrored on reads (both-sides involution).
__device__ __forceinline__ void async16(void* lds, const void* g) {
    __builtin_amdgcn_global_load_lds(
        (const __attribute__((address_space(1))) unsigned*)g,
        (__attribute__((address_space(3))) unsigned*)lds, 16, 0, 0);
}

// ===========================================================================
// Router: per-expert (token, weight) lists padded to x128 (tok=-1, w=0),
// tile table (128-slot tiles), and per-token slot map tok_slot[t][k].
__global__ void router_kernel(const int* __restrict__ te, const float* __restrict__ tw,
                              int* __restrict__ slot_tok, float* __restrict__ slot_w,
                              int* __restrict__ tok_slot,
                              int* __restrict__ tile_e, int* __restrict__ tile_s,
                              int* __restrict__ ntiles) {
    __shared__ int cnt[E_];
    __shared__ int s_any;
    int tid = threadIdx.x;
    if (tid < E_) cnt[tid] = 0;
    if (tid == 0) s_any = 0;
    __syncthreads();
    int any = 0;
    for (int i = tid; i < 2 * T_; i += 256) if (i & 1) any |= te[i];
    if (any) atomicOr(&s_any, 1);
    __syncthreads();
    bool is32 = (s_any != 0);      // int64 storage -> odd words all zero
    for (int t = tid; t < T_; t += 256) {
        int e0 = is32 ? te[2 * t]     : te[4 * t];
        int e1 = is32 ? te[2 * t + 1] : te[4 * t + 2];
        float w0 = tw[2 * t], w1 = tw[2 * t + 1];
        if (e0 == e1) {
            int p = atomicAdd(&cnt[e0], 1);
            int s = (p < SCAP) ? e0 * SCAP + p : -1;
            if (s >= 0) { slot_tok[s] = t; slot_w[s] = w0 + w1; }
            tok_slot[2 * t] = s; tok_slot[2 * t + 1] = -1;
        } else {
            int p = atomicAdd(&cnt[e0], 1);
            int s = (p < SCAP) ? e0 * SCAP + p : -1;
            if (s >= 0) { slot_tok[s] = t; slot_w[s] = w0; }
            tok_slot[2 * t] = s;
            p = atomicAdd(&cnt[e1], 1);
            s = (p < SCAP) ? e1 * SCAP + p : -1;
            if (s >= 0) { slot_tok[s] = t; slot_w[s] = w1; }
            tok_slot[2 * t + 1] = s;
        }
    }
    __syncthreads();
    for (int e = 0; e < E_; ++e) {
        int c = min(cnt[e], SCAP);
        int pc = min((c + 127) & ~127, SCAP);
        for (int p = c + tid; p < pc; p += 256) {
            slot_tok[e * SCAP + p] = -1; slot_w[e * SCAP + p] = 0.f;
        }
    }
    __syncthreads();
    if (tid == 0) {
        int nt = 0;
        for (int e = 0; e < E_; ++e) {
            int pc = min((min(cnt[e], SCAP) + 127) & ~127, SCAP);
            for (int s = 0; s < pc; s += 128) { tile_e[nt] = e; tile_s[nt] = e * SCAP + s; ++nt; }
        }
        *ntiles = nt;
    }
}

// f32 [F][H] -> bf16 [H][F] per expert (blockIdx.z), 64x64 tiles.
__global__ void tcvt8_kernel(const float* __restrict__ src0, u16* __restrict__ dst0) {
    const float* src = src0 + (size_t)blockIdx.z * F_ * H_;
    u16* dst = dst0 + (size_t)blockIdx.z * H_ * F_;
    __shared__ __align__(16) u16 tile[64][72];
    int bc = blockIdx.x * 64, br = blockIdx.y * 64;
    int tx = threadIdx.x, ty = threadIdx.y;   // (8,32)
    for (int r = ty; r < 64; r += 32) {
        const float* p = src + (size_t)(br + r) * H_ + bc + tx * 8;
        float4 v0 = *(const float4*)p;
        float4 v1 = *(const float4*)(p + 4);
        *(int4*)&tile[r][tx * 8] = cvt8(v0, v1);
    }
    __syncthreads();
    for (int c = ty; c < 64; c += 32) {
        u16 tmp[8];
#pragma unroll
        for (int j = 0; j < 8; ++j) tmp[j] = tile[tx * 8 + j][c];
        *(int4*)&dst[(size_t)(bc + c) * F_ + br + tx * 8] = *(int4*)tmp;
    }
}

// Gather+convert x rows into slot order: xg[slot][H] = bf16(x[tok]); zeros
// for sentinels. Grid (tile, 16): each block does 8 slots of a 128-slot tile.
__global__ void gather_x_kernel(const float* __restrict__ x, const int* __restrict__ slot_tok,
                                const int* __restrict__ tile_s, const int* __restrict__ ntiles,
                                u16* __restrict__ xg) {
    if ((int)blockIdx.x >= *ntiles) return;
    int base = tile_s[blockIdx.x];
    int tid = threadIdx.x;
    __shared__ int stok[128];
    if (tid < 128) stok[tid] = slot_tok[base + tid];
    __syncthreads();
    int c0 = blockIdx.y * 1024;                       // 8 slots x 128 chunks
    for (int c = c0 + tid; c < c0 + 1024; c += 256) { // 8-elem chunks
        int r = c >> 7, co = (c & 127) * 8;
        int tok = stok[r];
        u16* dst = xg + ((size_t)(base + r) << 10) + co;
        if (tok < 0) { *(int4*)dst = make_int4(0, 0, 0, 0); }
        else {
            const float* p = x + ((size_t)tok << 10) + co;
            *(int4*)dst = cvt8(*(const float4*)p, *(const float4*)(p + 4));
        }
    }
}

// ===========================================================================
// GLU GEMM: 128(slots) x 128(f), BK=32, 8 waves (512 thr), fused f32->bf16
// weight convert. A: async global_load_lds (1/thread/step). B1/B2: f32 reg
// loads (single set; reloaded in place each step), cvt_pk, 1 swizzled int4
// ds_write each. Per step:
//   cvt+write B(t)            (compiler waits B(t) regs only: vmcnt(1))
//   sched_barrier(0)          (loads may not hoist above -> no VGPR spike)
//   load B(t+1) regs          (overwrites consumed set -- no extra VGPR)
//   s_waitcnt vmcnt(4) lgkm(0)(pops A(t); B(t+1) RIDES ACROSS the barrier)
//   s_barrier
//   async A(t+1); 16 MFMA on buffers [cur]
// Cover for compulsory-HBM weight loads = barrier sync + A-issue + compute.
// VGPR=56 (<=64 boundary), LDS 49.6KB, 512 active blocks = 2/CU resident.
// grid = (f-tile 16, token-tile 48): same-(e,f0) blocks spaced 16 apart ->
// same XCD (id%8) -> weight slabs L2-shared across their 4 token tiles.
__global__ __launch_bounds__(512, 2) void glu_async_kernel(
        const u16* __restrict__ xg, const float* __restrict__ w1,
        const float* __restrict__ v1, const int* __restrict__ tile_e,
        const int* __restrict__ tile_s, const int* __restrict__ ntiles,
        const float* __restrict__ slot_w, u16* __restrict__ inter) {
    int bt = blockIdx.y;
    if (bt >= *ntiles) return;
    int e = tile_e[bt], s0 = tile_s[bt];
    int f0 = blockIdx.x * 128;
    __shared__ __align__(16) u16 As[2][128 * 32];    // 8 KB each
    __shared__ __align__(16) u16 B1s[2][128 * 32];
    __shared__ __align__(16) u16 B2s[2][128 * 32];
    __shared__ float swv[128];
    int tid = threadIdx.x;
    int lane = tid & 63, wave = tid >> 6;            // 0..7
    int wm = wave >> 2, wn = wave & 3;               // wm 0..1 (M), wn 0..3 (N)
    int ml = lane & 15, q = lane >> 4;
    if (tid < 128) swv[tid] = slot_w[s0 + tid];

    // staging geometry: row = tid>>2 (0..127), chunk = tid&3 (16B bf16 chunks)
    int arow = tid >> 2;
    int ach  = tid & 3;
    int swz  = (ach ^ ((arow >> 1) & 3));
    const u16* gA = xg + ((size_t)(s0 + arow) << 10) + (swz << 3);  // src-swz
    int lA = (arow << 5) + (ach << 3);               // linear LDS dest (elems)
    const size_t wofs = (size_t)e * F_ * H_;
    const float* gB1 = w1 + wofs + (size_t)(f0 + arow) * H_ + ach * 8;  // unswz
    const float* gB2 = v1 + wofs + (size_t)(f0 + arow) * H_ + ach * 8;
    int lB = (arow << 5) + (swz << 3);               // write-side swz

    // read-side swizzle: frag row R has (R>>1)&3 == (lane>>1)&3
    int xs = (q ^ ((lane >> 1) & 3)) << 3;

    f4v accg[4][2] = {};
    f4v accu[4][2] = {};

    // prologue: B(0) regs, A(0) async   [FIFO: B(0)x4, A(0)]
    float4 rb1a = *(const float4*)(gB1);
    float4 rb1b = *(const float4*)(gB1 + 4);
    float4 rb2a = *(const float4*)(gB2);
    float4 rb2b = *(const float4*)(gB2 + 4);
    async16(&As[0][lA], gA);

    const int NT = H_ / 32;                          // 32
    int cur = 0;
    for (int t = 0; t < NT; ++t) {
        // stage B(t): compiler's dependency waitcnt pops B(t) regs only
        *(int4*)(&B1s[cur][lB]) = cvt8(rb1a, rb1b);
        *(int4*)(&B2s[cur][lB]) = cvt8(rb2a, rb2b);
        __builtin_amdgcn_sched_barrier(0);           // loads stay below cvt
        if (t + 1 < NT) {
            int k = (t + 1) << 5;
            rb1a = *(const float4*)(gB1 + k);        // B(t+1), same regs
            rb1b = *(const float4*)(gB1 + k + 4);
            rb2a = *(const float4*)(gB2 + k);
            rb2b = *(const float4*)(gB2 + k + 4);
            // outstanding FIFO: [A(t), B(t+1)x4] -> pop A(t) only
            asm volatile("s_waitcnt vmcnt(4) lgkmcnt(0)" ::: "memory");
        } else {
            asm volatile("s_waitcnt vmcnt(0) lgkmcnt(0)" ::: "memory");
        }
        __builtin_amdgcn_s_barrier();
        __builtin_amdgcn_sched_barrier(0);
        if (t + 1 < NT)
            async16(&As[cur ^ 1][lA], gA + ((t + 1) << 5));   // A(t+1)
        s8v a[4];
#pragma unroll
        for (int i = 0; i < 4; ++i)
            a[i] = *(const s8v*)(&As[cur][(wm * 64 + i * 16 + ml) * 32 + xs]);
        {
            s8v b1[2];
#pragma unroll
            for (int j = 0; j < 2; ++j)
                b1[j] = *(const s8v*)(&B1s[cur][(wn * 32 + j * 16 + ml) * 32 + xs]);
#pragma unroll
            for (int i = 0; i < 4; ++i)
#pragma unroll
                for (int j = 0; j < 2; ++j)
                    accg[i][j] = __builtin_amdgcn_mfma_f32_16x16x32_bf16(a[i], b1[j], accg[i][j], 0, 0, 0);
        }
        {
            s8v b2[2];
#pragma unroll
            for (int j = 0; j < 2; ++j)
                b2[j] = *(const s8v*)(&B2s[cur][(wn * 32 + j * 16 + ml) * 32 + xs]);
#pragma unroll
            for (int i = 0; i < 4; ++i)
#pragma unroll
                for (int j = 0; j < 2; ++j)
                    accu[i][j] = __builtin_amdgcn_mfma_f32_16x16x32_bf16(a[i], b2[j], accu[i][j], 0, 0, 0);
        }
        cur ^= 1;
    }
#pragma unroll
    for (int i = 0; i < 4; ++i)
#pragma unroll
        for (int r = 0; r < 4; ++r) {
            int lr = wm * 64 + i * 16 + q * 4 + r;
            float cv = swv[lr];
#pragma unroll
            for (int j = 0; j < 2; ++j) {
                float g = accg[i][j][r];
                float u = accu[i][j][r];
                float s = g / (1.f + __expf(-g));
                int f = f0 + wn * 32 + j * 16 + ml;
                inter[((size_t)(s0 + lr) << 11) + f] = f2bf(cv * s * u);
            }
        }
}

// Down GEMM: 128(slots) x 128(h), BK=32, 8 waves (512 thr), K=F split x2
// into DISJOINT f32 buffers (slot-indexed, no atomics). 2-phase dbuf, both
// operands via async global_load_lds (1 each per thread per step).
// grid = (h-tile 8, token-tile 48, ksplit 2). 32.6KB LDS.
__global__ __launch_bounds__(512, 2) void down_async_kernel(
        const u16* __restrict__ inter, const u16* __restrict__ w2bT,
        const int* __restrict__ tile_e, const int* __restrict__ tile_s,
        const int* __restrict__ ntiles,
        float* __restrict__ dbufA, float* __restrict__ dbufB) {
    int bt = blockIdx.y;
    if (bt >= *ntiles) return;
    int e = tile_e[bt], s0 = tile_s[bt];
    int h0 = blockIdx.x * 128;
    int ks = blockIdx.z;
    int kbeg = ks * (F_ / 2);
    float* dbuf = ks ? dbufB : dbufA;
    __shared__ __align__(16) u16 As[2][128 * 32];    // 8 KB each
    __shared__ __align__(16) u16 Bs[2][128 * 32];
    int tid = threadIdx.x;
    int lane = tid & 63, wave = tid >> 6;
    int wm = wave >> 2, wn = wave & 3;
    int ml = lane & 15, q = lane >> 4;

    int arow = tid >> 2;
    int ach  = tid & 3;
    int swz  = (ach ^ ((arow >> 1) & 3));
    const u16* gA = inter + ((size_t)(s0 + arow) << 11) + kbeg + (swz << 3);
    const u16* gB = w2bT + (size_t)e * H_ * F_ + ((size_t)(h0 + arow) << 11) + kbeg + (swz << 3);
    int lA = (arow << 5) + (ach << 3);
    int xs = (q ^ ((lane >> 1) & 3)) << 3;

    f4v acc[4][2] = {};

    async16(&As[0][lA], gA);
    async16(&Bs[0][lA], gB);

    const int NT = (F_ / 2) / 32;                    // 32
    int cur = 0;
    for (int t = 0; t < NT; ++t) {
        __syncthreads();
        if (t + 1 < NT) {
            int k = (t + 1) << 5;
            async16(&As[cur ^ 1][lA], gA + k);
            async16(&Bs[cur ^ 1][lA], gB + k);
        }
        s8v a[4], b[2];
#pragma unroll
        for (int i = 0; i < 4; ++i)
            a[i] = *(const s8v*)(&As[cur][(wm * 64 + i * 16 + ml) * 32 + xs]);
#pragma unroll
        for (int j = 0; j < 2; ++j)
            b[j] = *(const s8v*)(&Bs[cur][(wn * 32 + j * 16 + ml) * 32 + xs]);
#pragma unroll
        for (int i = 0; i < 4; ++i)
#pragma unroll
            for (int j = 0; j < 2; ++j)
                acc[i][j] = __builtin_amdgcn_mfma_f32_16x16x32_bf16(a[i], b[j], acc[i][j], 0, 0, 0);
        cur ^= 1;
    }
#pragma unroll
    for (int i = 0; i < 4; ++i)
#pragma unroll
        for (int r = 0; r < 4; ++r) {
            int lr = wm * 64 + i * 16 + q * 4 + r;
            float* drow = dbuf + ((size_t)(s0 + lr) << 10);
#pragma unroll
            for (int j = 0; j < 2; ++j) {
                int h = h0 + wn * 32 + j * 16 + ml;
                drow[h] = acc[i][j][r];
            }
        }
}

// out[t][h] = sum over token's <=2 slots of (dbufA+dbufB). One block/token.
__global__ void combine_kernel(const float* __restrict__ dbufA, const float* __restrict__ dbufB,
                               const int* __restrict__ tok_slot, float* __restrict__ out) {
    int t = blockIdx.x;
    int c = threadIdx.x * 4;
    int s0 = tok_slot[2 * t], s1 = tok_slot[2 * t + 1];
    float4 acc = make_float4(0.f, 0.f, 0.f, 0.f);
    if (s0 >= 0) {
        float4 a = *(const float4*)(dbufA + ((size_t)s0 << 10) + c);
        float4 b = *(const float4*)(dbufB + ((size_t)s0 << 10) + c);
        acc.x = a.x + b.x; acc.y = a.y + b.y; acc.z = a.z + b.z; acc.w = a.w + b.w;
    }
    if (s1 >= 0) {
        float4 a = *(const float4*)(dbufA + ((size_t)s1 << 10) + c);
        float4 b = *(const float4*)(dbufB + ((size_t)s1 << 10) + c);
        acc.x += a.x + b.x; acc.y += a.y + b.y; acc.z += a.z + b.z; acc.w += a.w + b.w;
    }
    *(float4*)(out + ((size_t)t << 10) + c) = acc;
}

// ===========================================================================
// ================= Fallback: proven round-3 path (~69 MB) ==================
#define SCAP3 1024
__global__ void router3_kernel(const int* __restrict__ te, const float* __restrict__ tw,
                               int* __restrict__ cnt_g, int* __restrict__ slot_tok,
                               float* __restrict__ slot_w) {
    __shared__ int cnt[E_];
    __shared__ int s_any;
    int tid = threadIdx.x;
    if (tid < E_) cnt[tid] = 0;
    if (tid == 0) s_any = 0;
    __syncthreads();
    int any = 0;
    for (int i = tid; i < 2 * T_; i += 256) if (i & 1) any |= te[i];
    if (any) atomicOr(&s_any, 1);
    __syncthreads();
    bool is32 = (s_any != 0);
    for (int t = tid; t < T_; t += 256) {
        int e0 = is32 ? te[2 * t]     : te[4 * t];
        int e1 = is32 ? te[2 * t + 1] : te[4 * t + 2];
        float w0 = tw[2 * t], w1 = tw[2 * t + 1];
        if (e0 == e1) {
            int p = atomicAdd(&cnt[e0], 1);
            if (p < SCAP3) { slot_tok[e0 * SCAP3 + p] = t; slot_w[e0 * SCAP3 + p] = w0 + w1; }
        } else {
            int p = atomicAdd(&cnt[e0], 1);
            if (p < SCAP3) { slot_tok[e0 * SCAP3 + p] = t; slot_w[e0 * SCAP3 + p] = w0; }
            p = atomicAdd(&cnt[e1], 1);
            if (p < SCAP3) { slot_tok[e1 * SCAP3 + p] = t; slot_w[e1 * SCAP3 + p] = w1; }
        }
    }
    __syncthreads();
    for (int e = 0; e < E_; ++e) {
        int c = min(cnt[e], SCAP3);
        int pc = min((c + 127) & ~127, SCAP3);
        for (int p = c + tid; p < pc; p += 256) {
            slot_tok[e * SCAP3 + p] = 0; slot_w[e * SCAP3 + p] = 0.f;
        }
    }
    if (tid < E_) cnt_g[tid] = min(cnt[tid], SCAP3);
}
__global__ void cvt_kernel(const float* __restrict__ src, u16* __restrict__ dst) {
    int i = (blockIdx.x * 256 + threadIdx.x) * 4;
    float4 v = *(const float4*)(src + i);
    u16x4 o = { f2bf(v.x), f2bf(v.y), f2bf(v.z), f2bf(v.w) };
    *(u16x4*)(dst + i) = o;
}
__global__ __launch_bounds__(256, 2) void glu3_kernel(
        const u16* __restrict__ xb, const float* __restrict__ w1,
        const float* __restrict__ v1, const int* __restrict__ cnt_g,
        const int* __restrict__ slot_tok, const float* __restrict__ slot_w,
        u16* __restrict__ inter) {
    int e = blockIdx.x >> 3, tt = blockIdx.x & 7;
    if (tt * 128 >= cnt_g[e]) return;
    __shared__ __align__(16) u16 As[128 * 32];
    __shared__ __align__(16) u16 B1s[128 * 32];
    __shared__ __align__(16) u16 B2s[128 * 32];
    __shared__ int stok[128];
    __shared__ float sw[128];
    int tid = threadIdx.x;
    if (tid < 128) {
        stok[tid] = slot_tok[e * SCAP3 + tt * 128 + tid];
        sw[tid]   = slot_w[e * SCAP3 + tt * 128 + tid];
    }
    __syncthreads();
    int lane = tid & 63, wave = tid >> 6;
    int wm = wave >> 1, wn = wave & 1;
    int f0 = blockIdx.y * 128;
    int ml = lane & 15, q = lane >> 4;
    int r0 = tid >> 2, r1 = 64 + (tid >> 2);
    int colo = (tid & 3) * 8;
    const size_t tokoff0 = (size_t)stok[r0] * H_ + colo;
    const size_t tokoff1 = (size_t)stok[r1] * H_ + colo;
    const float* gb1 = w1 + (size_t)e * F_ * H_ + (size_t)f0 * H_;
    const float* gb2 = v1 + (size_t)e * F_ * H_ + (size_t)f0 * H_;
    const size_t boff0 = (size_t)r0 * H_ + colo;
    const size_t boff1 = (size_t)r1 * H_ + colo;
    f4v accg[4][4] = {};
    f4v accu[4][4] = {};
    for (int k0 = 0; k0 < H_; k0 += 32) {
        __syncthreads();
        *(int4*)(As + tid * 8)         = *(const int4*)(xb + tokoff0 + k0);
        *(int4*)(As + (256 + tid) * 8) = *(const int4*)(xb + tokoff1 + k0);
        const float* p = gb1 + boff0 + k0;
        *(int4*)(B1s + tid * 8) = cvt8(*(const float4*)p, *(const float4*)(p + 4));
        p = gb1 + boff1 + k0;
        *(int4*)(B1s + (256 + tid) * 8) = cvt8(*(const float4*)p, *(const float4*)(p + 4));
        p = gb2 + boff0 + k0;
        *(int4*)(B2s + tid * 8) = cvt8(*(const float4*)p, *(const float4*)(p + 4));
        p = gb2 + boff1 + k0;
        *(int4*)(B2s + (256 + tid) * 8) = cvt8(*(const float4*)p, *(const float4*)(p + 4));
        __syncthreads();
        s8v a[4], b1[4], b2[4];
#pragma unroll
        for (int i = 0; i < 4; ++i) {
            a[i]  = *(const s8v*)(As  + (wm * 64 + i * 16 + ml) * 32 + q * 8);
            b1[i] = *(const s8v*)(B1s + (wn * 64 + i * 16 + ml) * 32 + q * 8);
            b2[i] = *(const s8v*)(B2s + (wn * 64 + i * 16 + ml) * 32 + q * 8);
        }
#pragma unroll
        for (int i = 0; i < 4; ++i)
#pragma unroll
            for (int j = 0; j < 4; ++j) {
                accg[i][j] = __builtin_amdgcn_mfma_f32_16x16x32_bf16(a[i], b1[j], accg[i][j], 0, 0, 0);
                accu[i][j] = __builtin_amdgcn_mfma_f32_16x16x32_bf16(a[i], b2[j], accu[i][j], 0, 0, 0);
            }
    }
#pragma unroll
    for (int i = 0; i < 4; ++i)
#pragma unroll
        for (int r = 0; r < 4; ++r) {
            int lr = wm * 64 + i * 16 + q * 4 + r;
            float cv = sw[lr];
#pragma unroll
            for (int j = 0; j < 4; ++j) {
                float g = accg[i][j][r];
                float u = accu[i][j][r];
                float s = g / (1.f + __expf(-g));
                int f = f0 + wn * 64 + j * 16 + ml;
                inter[(size_t)(e * SCAP3 + tt * 128 + lr) * F_ + f] = f2bf(cv * s * u);
            }
        }
}
__global__ __launch_bounds__(256) void down3_kernel(
        const u16* __restrict__ inter, const u16* __restrict__ w2bT,
        const int* __restrict__ cnt_g, const int* __restrict__ slot_tok,
        float* __restrict__ out) {
    int e = blockIdx.x >> 3, tt = blockIdx.x & 7;
    if (tt * 128 >= cnt_g[e]) return;
    __shared__ __align__(16) u16 As[128 * 32];
    __shared__ __align__(16) u16 Bs[128 * 32];
    __shared__ int stok[128];
    int tid = threadIdx.x;
    if (tid < 128) stok[tid] = slot_tok[e * SCAP3 + tt * 128 + tid];
    __syncthreads();
    int lane = tid & 63, wave = tid >> 6;
    int wm = wave >> 1, wn = wave & 1;
    int h0 = blockIdx.y * 128;
    int ml = lane & 15, q = lane >> 4;
    int kbeg = blockIdx.z * (F_ / 2), kend = kbeg + (F_ / 2);
    f4v acc[4][4] = {};
    const u16* ga = inter + (size_t)(e * SCAP3 + tt * 128) * F_;
    const u16* gb = w2bT + (size_t)e * H_ * F_ + (size_t)h0 * F_;
    for (int k0 = kbeg; k0 < kend; k0 += 32) {
        __syncthreads();
#pragma unroll
        for (int p = 0; p < 2; ++p) {
            int c = p * 256 + tid;
            int r = c >> 2, co = (c & 3) * 8;
            *(int4*)(As + c * 8) = *(const int4*)(ga + (size_t)r * F_ + k0 + co);
            *(int4*)(Bs + c * 8) = *(const int4*)(gb + (size_t)r * F_ + k0 + co);
        }
        __syncthreads();
        s8v a[4], b[4];
#pragma unroll
        for (int i = 0; i < 4; ++i) {
            a[i] = *(const s8v*)(As + (wm * 64 + i * 16 + ml) * 32 + q * 8);
            b[i] = *(const s8v*)(Bs + (wn * 64 + i * 16 + ml) * 32 + q * 8);
        }
#pragma unroll
        for (int i = 0; i < 4; ++i)
#pragma unroll
            for (int j = 0; j < 4; ++j)
                acc[i][j] = __builtin_amdgcn_mfma_f32_16x16x32_bf16(a[i], b[j], acc[i][j], 0, 0, 0);
    }
#pragma unroll
    for (int i = 0; i < 4; ++i)
#pragma unroll
        for (int r = 0; r < 4; ++r) {
            int lr = wm * 64 + i * 16 + q * 4 + r;
            size_t trow = (size_t)stok[lr] * H_;
#pragma unroll
            for (int j = 0; j < 4; ++j) {
                int h = h0 + wn * 64 + j * 16 + ml;
                atomicAdd(&out[trow + h], acc[i][j][r]);
            }
        }
}

// ===========================================================================
extern "C" void kernel_launch(void* const* d_in, const int* in_sizes, int n_in,
                              void* d_out, int out_size, void* d_ws, size_t ws_size,
                              hipStream_t stream) {
    const float* x  = (const float*)d_in[0];
    const float* tw = (const float*)d_in[2];
    const int*   te = (const int*)d_in[3];
    const float* w1 = (const float*)d_in[4];
    const float* v1 = (const float*)d_in[5];
    const float* w2 = (const float*)d_in[6];
    float* out = (float*)d_out;
    char* ws = (char*)d_ws;

    if (ws_size >= ((size_t)135 << 20)) {
        // ---- primary async path ----
        // meta: ntiles@0, tile_e@256, tile_s@512, tok_slot@4K(16K),
        //       slot_tok@20K(24K), slot_w@44K(24K)
        // xg@1M(12M) | dbufA@13M(25.2M) | dbufB@45M(25.2M) | w2bT@77M(32M)
        // | inter@109M(24M).
        int*   ntiles   = (int*)(ws);
        int*   tile_e   = (int*)(ws + 256);
        int*   tile_s   = (int*)(ws + 512);
        int*   tok_slot = (int*)(ws + (4 << 10));
        int*   slot_tok = (int*)(ws + (20 << 10));
        float* slot_w   = (float*)(ws + (44 << 10));
        u16*   xg       = (u16*)(ws + ((size_t)1 << 20));
        u16*   w2bT     = (u16*)(ws + ((size_t)77 << 20));
        u16*   inter    = (u16*)(ws + ((size_t)109 << 20));
        float* dbufA    = (float*)(ws + ((size_t)13 << 20));   // 25.2 MB
        float* dbufB    = (float*)(ws + ((size_t)45 << 20));   // 25.2 MB

        router_kernel<<<1, 256, 0, stream>>>(te, tw, slot_tok, slot_w, tok_slot,
                                             tile_e, tile_s, ntiles);
        tcvt8_kernel<<<dim3(H_ / 64, F_ / 64, E_), dim3(8, 32), 0, stream>>>(w2, w2bT);
        gather_x_kernel<<<dim3(MAXT2, 16), 256, 0, stream>>>(x, slot_tok, tile_s, ntiles, xg);
        glu_async_kernel<<<dim3(F_ / 128, MAXT2), 512, 0, stream>>>(
            xg, w1, v1, tile_e, tile_s, ntiles, slot_w, inter);
        down_async_kernel<<<dim3(H_ / 128, MAXT2, 2), 512, 0, stream>>>(
            inter, w2bT, tile_e, tile_s, ntiles, dbufA, dbufB);
        combine_kernel<<<T_, 256, 0, stream>>>(dbufA, dbufB, tok_slot, out);
    } else {
        // ---- fallback: round-3 path (~69 MB, proven) ----
        int*   cnt_g    = (int*)(ws);
        int*   slot_tok = (int*)(ws + (4 << 10));
        float* slot_w   = (float*)(ws + (64 << 10));
        u16*   xb       = (u16*)(ws + ((size_t)1 << 20));
        u16*   w2bT    = (u16*)(ws + ((size_t)5 << 20));
        u16*   inter    = (u16*)(ws + ((size_t)37 << 20));

        hipMemsetAsync(out, 0, (size_t)T_ * H_ * sizeof(float), stream);
        router3_kernel<<<1, 256, 0, stream>>>(te, tw, cnt_g, slot_tok, slot_w);
        cvt_kernel<<<(T_ * H_) / 1024, 256, 0, stream>>>(x, xb);
        tcvt8_kernel<<<dim3(H_ / 64, F_ / 64, E_), dim3(8, 32), 0, stream>>>(w2, w2bT);
        glu3_kernel<<<dim3(E_ * 8, F_ / 128), 256, 0, stream>>>(
            xb, w1, v1, cnt_g, slot_tok, slot_w, inter);
        down3_kernel<<<dim3(E_ * 8, H_ / 128, 2), 256, 0, stream>>>(
            inter, w2bT, cnt_g, slot_tok, out);
    }
}

// Round 11
// 306.306 us; speedup vs baseline: 1.0222x; 1.0222x over previous
//
#include <hip/hip_runtime.h>
#include <hip/hip_bf16.h>

// DBRX MoE experts forward, MI355X gfx950.
// T=2048, H=1024, F=2048, E=8, K=2. f32 storage in/out; bf16 MFMA compute.
// Round 17: r16's validated recipe (zero-new-resource counted-vmcnt across
// a raw s_barrier) applied to down. glu unchanged from r16 (88->78us
// proven). down goes TRIPLE-buffered -- free at 128^2 tile: LDS 32.6->48.6
// KB but grid is exactly 768 = 3 blocks/CU and 48.6x3 = 146 <= 160 KB, so
// residency unchanged. Per step: wait "vmcnt(2) lgkmcnt(0)" (pops the
// t-pair, drains ds_reads -> safe to overwrite buf (t-1)%3), s_barrier,
// issue t+2 pair post-barrier, compute buf t%3. Each load pair now gets
// ~2 full steps of cover instead of <1. Tail drains vmcnt(2)->vmcnt(0).
// gather_x reverted to r15's 48x8 grid (r16's 48x16 cost ~10us: 2x blocks
// each loading 128 stok for 8 used slots). Fallback path unchanged.

#define T_ 2048
#define H_ 1024
#define F_ 2048
#define E_ 8

#define SCAP 768                  // per-expert slot capacity (multiple of 128)
#define NSLOT (E_ * SCAP)         // 6144
#define MAXT2 (NSLOT / 128)       // 48 max 128-slot tiles

typedef unsigned short u16;
typedef short s8v __attribute__((ext_vector_type(8)));
typedef float f4v __attribute__((ext_vector_type(4)));
typedef unsigned short u16x4 __attribute__((ext_vector_type(4)));

__device__ __forceinline__ u16 f2bf(float f) {
    union { float f; unsigned u; } v; v.f = f;
    unsigned r = v.u + 0x7FFF + ((v.u >> 16) & 1);   // RNE
    return (u16)(r >> 16);
}
__device__ __forceinline__ unsigned pkbf(float a, float b) {
    __hip_bfloat162 h = __float22bfloat162_rn(make_float2(a, b));
    union { __hip_bfloat162 h; unsigned u; } c; c.h = h; return c.u;
}
__device__ __forceinline__ int4 cvt8(const float4 a, const float4 b) {
    int4 r; r.x = (int)pkbf(a.x, a.y); r.y = (int)pkbf(a.z, a.w);
    r.z = (int)pkbf(b.x, b.y); r.w = (int)pkbf(b.z, b.w); return r;
}
// async 16B/lane global->LDS; LDS dest stays LINEAR (wave base + lane*16).
// Swizzle applied on the GLOBAL source chunk (chunk ^ ((row>>1)&3)) and
// mirrored on reads (both-sides involution).
__device__ __forceinline__ void async16(void* lds, const void* g) {
    __builtin_amdgcn_global_load_lds(
        (const __attribute__((address_space(1))) unsigned*)g,
        (__attribute__((address_space(3))) unsigned*)lds, 16, 0, 0);
}

// ===========================================================================
// Router: per-expert (token, weight) lists padded to x128 (tok=-1, w=0),
// tile table (128-slot tiles), and per-token slot map tok_slot[t][k].
__global__ void router_kernel(const int* __restrict__ te, const float* __restrict__ tw,
                              int* __restrict__ slot_tok, float* __restrict__ slot_w,
                              int* __restrict__ tok_slot,
                              int* __restrict__ tile_e, int* __restrict__ tile_s,
                              int* __restrict__ ntiles) {
    __shared__ int cnt[E_];
    __shared__ int s_any;
    int tid = threadIdx.x;
    if (tid < E_) cnt[tid] = 0;
    if (tid == 0) s_any = 0;
    __syncthreads();
    int any = 0;
    for (int i = tid; i < 2 * T_; i += 256) if (i & 1) any |= te[i];
    if (any) atomicOr(&s_any, 1);
    __syncthreads();
    bool is32 = (s_any != 0);      // int64 storage -> odd words all zero
    for (int t = tid; t < T_; t += 256) {
        int e0 = is32 ? te[2 * t]     : te[4 * t];
        int e1 = is32 ? te[2 * t + 1] : te[4 * t + 2];
        float w0 = tw[2 * t], w1 = tw[2 * t + 1];
        if (e0 == e1) {
            int p = atomicAdd(&cnt[e0], 1);
            int s = (p < SCAP) ? e0 * SCAP + p : -1;
            if (s >= 0) { slot_tok[s] = t; slot_w[s] = w0 + w1; }
            tok_slot[2 * t] = s; tok_slot[2 * t + 1] = -1;
        } else {
            int p = atomicAdd(&cnt[e0], 1);
            int s = (p < SCAP) ? e0 * SCAP + p : -1;
            if (s >= 0) { slot_tok[s] = t; slot_w[s] = w0; }
            tok_slot[2 * t] = s;
            p = atomicAdd(&cnt[e1], 1);
            s = (p < SCAP) ? e1 * SCAP + p : -1;
            if (s >= 0) { slot_tok[s] = t; slot_w[s] = w1; }
            tok_slot[2 * t + 1] = s;
        }
    }
    __syncthreads();
    for (int e = 0; e < E_; ++e) {
        int c = min(cnt[e], SCAP);
        int pc = min((c + 127) & ~127, SCAP);
        for (int p = c + tid; p < pc; p += 256) {
            slot_tok[e * SCAP + p] = -1; slot_w[e * SCAP + p] = 0.f;
        }
    }
    __syncthreads();
    if (tid == 0) {
        int nt = 0;
        for (int e = 0; e < E_; ++e) {
            int pc = min((min(cnt[e], SCAP) + 127) & ~127, SCAP);
            for (int s = 0; s < pc; s += 128) { tile_e[nt] = e; tile_s[nt] = e * SCAP + s; ++nt; }
        }
        *ntiles = nt;
    }
}

// f32 [F][H] -> bf16 [H][F] per expert (blockIdx.z), 64x64 tiles.
__global__ void tcvt8_kernel(const float* __restrict__ src0, u16* __restrict__ dst0) {
    const float* src = src0 + (size_t)blockIdx.z * F_ * H_;
    u16* dst = dst0 + (size_t)blockIdx.z * H_ * F_;
    __shared__ __align__(16) u16 tile[64][72];
    int bc = blockIdx.x * 64, br = blockIdx.y * 64;
    int tx = threadIdx.x, ty = threadIdx.y;   // (8,32)
    for (int r = ty; r < 64; r += 32) {
        const float* p = src + (size_t)(br + r) * H_ + bc + tx * 8;
        float4 v0 = *(const float4*)p;
        float4 v1 = *(const float4*)(p + 4);
        *(int4*)&tile[r][tx * 8] = cvt8(v0, v1);
    }
    __syncthreads();
    for (int c = ty; c < 64; c += 32) {
        u16 tmp[8];
#pragma unroll
        for (int j = 0; j < 8; ++j) tmp[j] = tile[tx * 8 + j][c];
        *(int4*)&dst[(size_t)(bc + c) * F_ + br + tx * 8] = *(int4*)tmp;
    }
}

// Gather+convert x rows into slot order: xg[slot][H] = bf16(x[tok]); zeros
// for sentinels. Grid (tile, 8): each block does 16 slots of a 128-slot tile.
__global__ void gather_x_kernel(const float* __restrict__ x, const int* __restrict__ slot_tok,
                                const int* __restrict__ tile_s, const int* __restrict__ ntiles,
                                u16* __restrict__ xg) {
    if ((int)blockIdx.x >= *ntiles) return;
    int base = tile_s[blockIdx.x];
    int tid = threadIdx.x;
    __shared__ int stok[128];
    if (tid < 128) stok[tid] = slot_tok[base + tid];
    __syncthreads();
    int c0 = blockIdx.y * 2048;                       // 16 slots x 128 chunks
    for (int c = c0 + tid; c < c0 + 2048; c += 256) { // 8-elem chunks
        int r = c >> 7, co = (c & 127) * 8;
        int tok = stok[r];
        u16* dst = xg + ((size_t)(base + r) << 10) + co;
        if (tok < 0) { *(int4*)dst = make_int4(0, 0, 0, 0); }
        else {
            const float* p = x + ((size_t)tok << 10) + co;
            *(int4*)dst = cvt8(*(const float4*)p, *(const float4*)(p + 4));
        }
    }
}

// ===========================================================================
// GLU GEMM: 128(slots) x 128(f), BK=32, 8 waves (512 thr), fused f32->bf16
// weight convert. A: async global_load_lds (1/thread/step). B1/B2: f32 reg
// loads (single set; reloaded in place each step), cvt_pk, 1 swizzled int4
// ds_write each. Per step (r16, proven 88->78us):
//   cvt+write B(t); sched_barrier; load B(t+1) regs;
//   s_waitcnt vmcnt(4) lgkm(0)  (pops A(t); B(t+1) rides across barrier)
//   s_barrier; async A(t+1); 16 MFMA.
// VGPR=64 (at boundary, verified OK), LDS 49.6KB, 2 blocks/CU resident.
__global__ __launch_bounds__(512, 2) void glu_async_kernel(
        const u16* __restrict__ xg, const float* __restrict__ w1,
        const float* __restrict__ v1, const int* __restrict__ tile_e,
        const int* __restrict__ tile_s, const int* __restrict__ ntiles,
        const float* __restrict__ slot_w, u16* __restrict__ inter) {
    int bt = blockIdx.y;
    if (bt >= *ntiles) return;
    int e = tile_e[bt], s0 = tile_s[bt];
    int f0 = blockIdx.x * 128;
    __shared__ __align__(16) u16 As[2][128 * 32];    // 8 KB each
    __shared__ __align__(16) u16 B1s[2][128 * 32];
    __shared__ __align__(16) u16 B2s[2][128 * 32];
    __shared__ float swv[128];
    int tid = threadIdx.x;
    int lane = tid & 63, wave = tid >> 6;            // 0..7
    int wm = wave >> 2, wn = wave & 3;               // wm 0..1 (M), wn 0..3 (N)
    int ml = lane & 15, q = lane >> 4;
    if (tid < 128) swv[tid] = slot_w[s0 + tid];

    // staging geometry: row = tid>>2 (0..127), chunk = tid&3 (16B bf16 chunks)
    int arow = tid >> 2;
    int ach  = tid & 3;
    int swz  = (ach ^ ((arow >> 1) & 3));
    const u16* gA = xg + ((size_t)(s0 + arow) << 10) + (swz << 3);  // src-swz
    int lA = (arow << 5) + (ach << 3);               // linear LDS dest (elems)
    const size_t wofs = (size_t)e * F_ * H_;
    const float* gB1 = w1 + wofs + (size_t)(f0 + arow) * H_ + ach * 8;  // unswz
    const float* gB2 = v1 + wofs + (size_t)(f0 + arow) * H_ + ach * 8;
    int lB = (arow << 5) + (swz << 3);               // write-side swz

    // read-side swizzle: frag row R has (R>>1)&3 == (lane>>1)&3
    int xs = (q ^ ((lane >> 1) & 3)) << 3;

    f4v accg[4][2] = {};
    f4v accu[4][2] = {};

    // prologue: B(0) regs, A(0) async   [FIFO: B(0)x4, A(0)]
    float4 rb1a = *(const float4*)(gB1);
    float4 rb1b = *(const float4*)(gB1 + 4);
    float4 rb2a = *(const float4*)(gB2);
    float4 rb2b = *(const float4*)(gB2 + 4);
    async16(&As[0][lA], gA);

    const int NT = H_ / 32;                          // 32
    int cur = 0;
    for (int t = 0; t < NT; ++t) {
        // stage B(t): compiler's dependency waitcnt pops B(t) regs only
        *(int4*)(&B1s[cur][lB]) = cvt8(rb1a, rb1b);
        *(int4*)(&B2s[cur][lB]) = cvt8(rb2a, rb2b);
        __builtin_amdgcn_sched_barrier(0);           // loads stay below cvt
        if (t + 1 < NT) {
            int k = (t + 1) << 5;
            rb1a = *(const float4*)(gB1 + k);        // B(t+1), same regs
            rb1b = *(const float4*)(gB1 + k + 4);
            rb2a = *(const float4*)(gB2 + k);
            rb2b = *(const float4*)(gB2 + k + 4);
            // outstanding FIFO: [A(t), B(t+1)x4] -> pop A(t) only
            asm volatile("s_waitcnt vmcnt(4) lgkmcnt(0)" ::: "memory");
        } else {
            asm volatile("s_waitcnt vmcnt(0) lgkmcnt(0)" ::: "memory");
        }
        __builtin_amdgcn_s_barrier();
        __builtin_amdgcn_sched_barrier(0);
        if (t + 1 < NT)
            async16(&As[cur ^ 1][lA], gA + ((t + 1) << 5));   // A(t+1)
        s8v a[4];
#pragma unroll
        for (int i = 0; i < 4; ++i)
            a[i] = *(const s8v*)(&As[cur][(wm * 64 + i * 16 + ml) * 32 + xs]);
        {
            s8v b1[2];
#pragma unroll
            for (int j = 0; j < 2; ++j)
                b1[j] = *(const s8v*)(&B1s[cur][(wn * 32 + j * 16 + ml) * 32 + xs]);
#pragma unroll
            for (int i = 0; i < 4; ++i)
#pragma unroll
                for (int j = 0; j < 2; ++j)
                    accg[i][j] = __builtin_amdgcn_mfma_f32_16x16x32_bf16(a[i], b1[j], accg[i][j], 0, 0, 0);
        }
        {
            s8v b2[2];
#pragma unroll
            for (int j = 0; j < 2; ++j)
                b2[j] = *(const s8v*)(&B2s[cur][(wn * 32 + j * 16 + ml) * 32 + xs]);
#pragma unroll
            for (int i = 0; i < 4; ++i)
#pragma unroll
                for (int j = 0; j < 2; ++j)
                    accu[i][j] = __builtin_amdgcn_mfma_f32_16x16x32_bf16(a[i], b2[j], accu[i][j], 0, 0, 0);
        }
        cur ^= 1;
    }
#pragma unroll
    for (int i = 0; i < 4; ++i)
#pragma unroll
        for (int r = 0; r < 4; ++r) {
            int lr = wm * 64 + i * 16 + q * 4 + r;
            float cv = swv[lr];
#pragma unroll
            for (int j = 0; j < 2; ++j) {
                float g = accg[i][j][r];
                float u = accu[i][j][r];
                float s = g / (1.f + __expf(-g));
                int f = f0 + wn * 32 + j * 16 + ml;
                inter[((size_t)(s0 + lr) << 11) + f] = f2bf(cv * s * u);
            }
        }
}

// Down GEMM: 128(slots) x 128(h), BK=32, 8 waves (512 thr), K=F split x2
// into DISJOINT f32 buffers (slot-indexed, no atomics). TRIPLE-buffered
// counted-vmcnt pipeline (r16 recipe): per step,
//   s_waitcnt vmcnt(2) lgkmcnt(0)  (pops [A(t),B(t)]; [A(t+1),B(t+1)] ride;
//                                   lgkm drain -> safe to overwrite buf t-1)
//   s_barrier; issue [A(t+2),B(t+2)] into buf (t+2)%3; compute buf t%3.
// Each load pair gets ~2 full steps of cover. LDS 48.6KB x 3 blocks/CU =
// 146KB <= 160 -> residency UNCHANGED (grid = 768 = 256 CU x 3).
// grid = (h-tile 8, token-tile 48, ksplit 2).
__global__ __launch_bounds__(512, 2) void down_async_kernel(
        const u16* __restrict__ inter, const u16* __restrict__ w2bT,
        const int* __restrict__ tile_e, const int* __restrict__ tile_s,
        const int* __restrict__ ntiles,
        float* __restrict__ dbufA, float* __restrict__ dbufB) {
    int bt = blockIdx.y;
    if (bt >= *ntiles) return;
    int e = tile_e[bt], s0 = tile_s[bt];
    int h0 = blockIdx.x * 128;
    int ks = blockIdx.z;
    int kbeg = ks * (F_ / 2);
    float* dbuf = ks ? dbufB : dbufA;
    __shared__ __align__(16) u16 As[3][128 * 32];    // 8 KB each
    __shared__ __align__(16) u16 Bs[3][128 * 32];
    int tid = threadIdx.x;
    int lane = tid & 63, wave = tid >> 6;
    int wm = wave >> 2, wn = wave & 3;
    int ml = lane & 15, q = lane >> 4;

    int arow = tid >> 2;
    int ach  = tid & 3;
    int swz  = (ach ^ ((arow >> 1) & 3));
    const u16* gA = inter + ((size_t)(s0 + arow) << 11) + kbeg + (swz << 3);
    const u16* gB = w2bT + (size_t)e * H_ * F_ + ((size_t)(h0 + arow) << 11) + kbeg + (swz << 3);
    int lA = (arow << 5) + (ach << 3);
    int xs = (q ^ ((lane >> 1) & 3)) << 3;

    f4v acc[4][2] = {};

    // prologue: tiles 0 and 1   [FIFO: A0,B0,A1,B1]
    async16(&As[0][lA], gA);
    async16(&Bs[0][lA], gB);
    async16(&As[1][lA], gA + 32);
    async16(&Bs[1][lA], gB + 32);

    const int NT = (F_ / 2) / 32;                    // 32
    int cur = 0, nb = 2;                             // compute buf, fill buf
    for (int t = 0; t < NT; ++t) {
        if (t + 1 < NT) asm volatile("s_waitcnt vmcnt(2) lgkmcnt(0)" ::: "memory");
        else            asm volatile("s_waitcnt vmcnt(0) lgkmcnt(0)" ::: "memory");
        __builtin_amdgcn_s_barrier();
        __builtin_amdgcn_sched_barrier(0);
        if (t + 2 < NT) {
            int k = (t + 2) << 5;
            async16(&As[nb][lA], gA + k);
            async16(&Bs[nb][lA], gB + k);
        }
        s8v a[4], b[2];
#pragma unroll
        for (int i = 0; i < 4; ++i)
            a[i] = *(const s8v*)(&As[cur][(wm * 64 + i * 16 + ml) * 32 + xs]);
#pragma unroll
        for (int j = 0; j < 2; ++j)
            b[j] = *(const s8v*)(&Bs[cur][(wn * 32 + j * 16 + ml) * 32 + xs]);
#pragma unroll
        for (int i = 0; i < 4; ++i)
#pragma unroll
            for (int j = 0; j < 2; ++j)
                acc[i][j] = __builtin_amdgcn_mfma_f32_16x16x32_bf16(a[i], b[j], acc[i][j], 0, 0, 0);
        int cn = cur + 1; cur = (cn == 3) ? 0 : cn;
        cn = nb + 1; nb = (cn == 3) ? 0 : cn;
    }
#pragma unroll
    for (int i = 0; i < 4; ++i)
#pragma unroll
        for (int r = 0; r < 4; ++r) {
            int lr = wm * 64 + i * 16 + q * 4 + r;
            float* drow = dbuf + ((size_t)(s0 + lr) << 10);
#pragma unroll
            for (int j = 0; j < 2; ++j) {
                int h = h0 + wn * 32 + j * 16 + ml;
                drow[h] = acc[i][j][r];
            }
        }
}

// out[t][h] = sum over token's <=2 slots of (dbufA+dbufB). One block/token.
__global__ void combine_kernel(const float* __restrict__ dbufA, const float* __restrict__ dbufB,
                               const int* __restrict__ tok_slot, float* __restrict__ out) {
    int t = blockIdx.x;
    int c = threadIdx.x * 4;
    int s0 = tok_slot[2 * t], s1 = tok_slot[2 * t + 1];
    float4 acc = make_float4(0.f, 0.f, 0.f, 0.f);
    if (s0 >= 0) {
        float4 a = *(const float4*)(dbufA + ((size_t)s0 << 10) + c);
        float4 b = *(const float4*)(dbufB + ((size_t)s0 << 10) + c);
        acc.x = a.x + b.x; acc.y = a.y + b.y; acc.z = a.z + b.z; acc.w = a.w + b.w;
    }
    if (s1 >= 0) {
        float4 a = *(const float4*)(dbufA + ((size_t)s1 << 10) + c);
        float4 b = *(const float4*)(dbufB + ((size_t)s1 << 10) + c);
        acc.x += a.x + b.x; acc.y += a.y + b.y; acc.z += a.z + b.z; acc.w += a.w + b.w;
    }
    *(float4*)(out + ((size_t)t << 10) + c) = acc;
}

// ===========================================================================
// ================= Fallback: proven round-3 path (~69 MB) ==================
#define SCAP3 1024
__global__ void router3_kernel(const int* __restrict__ te, const float* __restrict__ tw,
                               int* __restrict__ cnt_g, int* __restrict__ slot_tok,
                               float* __restrict__ slot_w) {
    __shared__ int cnt[E_];
    __shared__ int s_any;
    int tid = threadIdx.x;
    if (tid < E_) cnt[tid] = 0;
    if (tid == 0) s_any = 0;
    __syncthreads();
    int any = 0;
    for (int i = tid; i < 2 * T_; i += 256) if (i & 1) any |= te[i];
    if (any) atomicOr(&s_any, 1);
    __syncthreads();
    bool is32 = (s_any != 0);
    for (int t = tid; t < T_; t += 256) {
        int e0 = is32 ? te[2 * t]     : te[4 * t];
        int e1 = is32 ? te[2 * t + 1] : te[4 * t + 2];
        float w0 = tw[2 * t], w1 = tw[2 * t + 1];
        if (e0 == e1) {
            int p = atomicAdd(&cnt[e0], 1);
            if (p < SCAP3) { slot_tok[e0 * SCAP3 + p] = t; slot_w[e0 * SCAP3 + p] = w0 + w1; }
        } else {
            int p = atomicAdd(&cnt[e0], 1);
            if (p < SCAP3) { slot_tok[e0 * SCAP3 + p] = t; slot_w[e0 * SCAP3 + p] = w0; }
            p = atomicAdd(&cnt[e1], 1);
            if (p < SCAP3) { slot_tok[e1 * SCAP3 + p] = t; slot_w[e1 * SCAP3 + p] = w1; }
        }
    }
    __syncthreads();
    for (int e = 0; e < E_; ++e) {
        int c = min(cnt[e], SCAP3);
        int pc = min((c + 127) & ~127, SCAP3);
        for (int p = c + tid; p < pc; p += 256) {
            slot_tok[e * SCAP3 + p] = 0; slot_w[e * SCAP3 + p] = 0.f;
        }
    }
    if (tid < E_) cnt_g[tid] = min(cnt[tid], SCAP3);
}
__global__ void cvt_kernel(const float* __restrict__ src, u16* __restrict__ dst) {
    int i = (blockIdx.x * 256 + threadIdx.x) * 4;
    float4 v = *(const float4*)(src + i);
    u16x4 o = { f2bf(v.x), f2bf(v.y), f2bf(v.z), f2bf(v.w) };
    *(u16x4*)(dst + i) = o;
}
__global__ __launch_bounds__(256, 2) void glu3_kernel(
        const u16* __restrict__ xb, const float* __restrict__ w1,
        const float* __restrict__ v1, const int* __restrict__ cnt_g,
        const int* __restrict__ slot_tok, const float* __restrict__ slot_w,
        u16* __restrict__ inter) {
    int e = blockIdx.x >> 3, tt = blockIdx.x & 7;
    if (tt * 128 >= cnt_g[e]) return;
    __shared__ __align__(16) u16 As[128 * 32];
    __shared__ __align__(16) u16 B1s[128 * 32];
    __shared__ __align__(16) u16 B2s[128 * 32];
    __shared__ int stok[128];
    __shared__ float sw[128];
    int tid = threadIdx.x;
    if (tid < 128) {
        stok[tid] = slot_tok[e * SCAP3 + tt * 128 + tid];
        sw[tid]   = slot_w[e * SCAP3 + tt * 128 + tid];
    }
    __syncthreads();
    int lane = tid & 63, wave = tid >> 6;
    int wm = wave >> 1, wn = wave & 1;
    int f0 = blockIdx.y * 128;
    int ml = lane & 15, q = lane >> 4;
    int r0 = tid >> 2, r1 = 64 + (tid >> 2);
    int colo = (tid & 3) * 8;
    const size_t tokoff0 = (size_t)stok[r0] * H_ + colo;
    const size_t tokoff1 = (size_t)stok[r1] * H_ + colo;
    const float* gb1 = w1 + (size_t)e * F_ * H_ + (size_t)f0 * H_;
    const float* gb2 = v1 + (size_t)e * F_ * H_ + (size_t)f0 * H_;
    const size_t boff0 = (size_t)r0 * H_ + colo;
    const size_t boff1 = (size_t)r1 * H_ + colo;
    f4v accg[4][4] = {};
    f4v accu[4][4] = {};
    for (int k0 = 0; k0 < H_; k0 += 32) {
        __syncthreads();
        *(int4*)(As + tid * 8)         = *(const int4*)(xb + tokoff0 + k0);
        *(int4*)(As + (256 + tid) * 8) = *(const int4*)(xb + tokoff1 + k0);
        const float* p = gb1 + boff0 + k0;
        *(int4*)(B1s + tid * 8) = cvt8(*(const float4*)p, *(const float4*)(p + 4));
        p = gb1 + boff1 + k0;
        *(int4*)(B1s + (256 + tid) * 8) = cvt8(*(const float4*)p, *(const float4*)(p + 4));
        p = gb2 + boff0 + k0;
        *(int4*)(B2s + tid * 8) = cvt8(*(const float4*)p, *(const float4*)(p + 4));
        p = gb2 + boff1 + k0;
        *(int4*)(B2s + (256 + tid) * 8) = cvt8(*(const float4*)p, *(const float4*)(p + 4));
        __syncthreads();
        s8v a[4], b1[4], b2[4];
#pragma unroll
        for (int i = 0; i < 4; ++i) {
            a[i]  = *(const s8v*)(As  + (wm * 64 + i * 16 + ml) * 32 + q * 8);
            b1[i] = *(const s8v*)(B1s + (wn * 64 + i * 16 + ml) * 32 + q * 8);
            b2[i] = *(const s8v*)(B2s + (wn * 64 + i * 16 + ml) * 32 + q * 8);
        }
#pragma unroll
        for (int i = 0; i < 4; ++i)
#pragma unroll
            for (int j = 0; j < 4; ++j) {
                accg[i][j] = __builtin_amdgcn_mfma_f32_16x16x32_bf16(a[i], b1[j], accg[i][j], 0, 0, 0);
                accu[i][j] = __builtin_amdgcn_mfma_f32_16x16x32_bf16(a[i], b2[j], accu[i][j], 0, 0, 0);
            }
    }
#pragma unroll
    for (int i = 0; i < 4; ++i)
#pragma unroll
        for (int r = 0; r < 4; ++r) {
            int lr = wm * 64 + i * 16 + q * 4 + r;
            float cv = sw[lr];
#pragma unroll
            for (int j = 0; j < 4; ++j) {
                float g = accg[i][j][r];
                float u = accu[i][j][r];
                float s = g / (1.f + __expf(-g));
                int f = f0 + wn * 64 + j * 16 + ml;
                inter[(size_t)(e * SCAP3 + tt * 128 + lr) * F_ + f] = f2bf(cv * s * u);
            }
        }
}
__global__ __launch_bounds__(256) void down3_kernel(
        const u16* __restrict__ inter, const u16* __restrict__ w2bT,
        const int* __restrict__ cnt_g, const int* __restrict__ slot_tok,
        float* __restrict__ out) {
    int e = blockIdx.x >> 3, tt = blockIdx.x & 7;
    if (tt * 128 >= cnt_g[e]) return;
    __shared__ __align__(16) u16 As[128 * 32];
    __shared__ __align__(16) u16 Bs[128 * 32];
    __shared__ int stok[128];
    int tid = threadIdx.x;
    if (tid < 128) stok[tid] = slot_tok[e * SCAP3 + tt * 128 + tid];
    __syncthreads();
    int lane = tid & 63, wave = tid >> 6;
    int wm = wave >> 1, wn = wave & 1;
    int h0 = blockIdx.y * 128;
    int ml = lane & 15, q = lane >> 4;
    int kbeg = blockIdx.z * (F_ / 2), kend = kbeg + (F_ / 2);
    f4v acc[4][4] = {};
    const u16* ga = inter + (size_t)(e * SCAP3 + tt * 128) * F_;
    const u16* gb = w2bT + (size_t)e * H_ * F_ + (size_t)h0 * F_;
    for (int k0 = kbeg; k0 < kend; k0 += 32) {
        __syncthreads();
#pragma unroll
        for (int p = 0; p < 2; ++p) {
            int c = p * 256 + tid;
            int r = c >> 2, co = (c & 3) * 8;
            *(int4*)(As + c * 8) = *(const int4*)(ga + (size_t)r * F_ + k0 + co);
            *(int4*)(Bs + c * 8) = *(const int4*)(gb + (size_t)r * F_ + k0 + co);
        }
        __syncthreads();
        s8v a[4], b[4];
#pragma unroll
        for (int i = 0; i < 4; ++i) {
            a[i] = *(const s8v*)(As + (wm * 64 + i * 16 + ml) * 32 + q * 8);
            b[i] = *(const s8v*)(Bs + (wn * 64 + i * 16 + ml) * 32 + q * 8);
        }
#pragma unroll
        for (int i = 0; i < 4; ++i)
#pragma unroll
            for (int j = 0; j < 4; ++j)
                acc[i][j] = __builtin_amdgcn_mfma_f32_16x16x32_bf16(a[i], b[j], acc[i][j], 0, 0, 0);
    }
#pragma unroll
    for (int i = 0; i < 4; ++i)
#pragma unroll
        for (int r = 0; r < 4; ++r) {
            int lr = wm * 64 + i * 16 + q * 4 + r;
            size_t trow = (size_t)stok[lr] * H_;
#pragma unroll
            for (int j = 0; j < 4; ++j) {
                int h = h0 + wn * 64 + j * 16 + ml;
                atomicAdd(&out[trow + h], acc[i][j][r]);
            }
        }
}

// ===========================================================================
extern "C" void kernel_launch(void* const* d_in, const int* in_sizes, int n_in,
                              void* d_out, int out_size, void* d_ws, size_t ws_size,
                              hipStream_t stream) {
    const float* x  = (const float*)d_in[0];
    const float* tw = (const float*)d_in[2];
    const int*   te = (const int*)d_in[3];
    const float* w1 = (const float*)d_in[4];
    const float* v1 = (const float*)d_in[5];
    const float* w2 = (const float*)d_in[6];
    float* out = (float*)d_out;
    char* ws = (char*)d_ws;

    if (ws_size >= ((size_t)135 << 20)) {
        // ---- primary async path ----
        // meta: ntiles@0, tile_e@256, tile_s@512, tok_slot@4K(16K),
        //       slot_tok@20K(24K), slot_w@44K(24K)
        // xg@1M(12M) | dbufA@13M(25.2M) | dbufB@45M(25.2M) | w2bT@77M(32M)
        // | inter@109M(24M).
        int*   ntiles   = (int*)(ws);
        int*   tile_e   = (int*)(ws + 256);
        int*   tile_s   = (int*)(ws + 512);
        int*   tok_slot = (int*)(ws + (4 << 10));
        int*   slot_tok = (int*)(ws + (20 << 10));
        float* slot_w   = (float*)(ws + (44 << 10));
        u16*   xg       = (u16*)(ws + ((size_t)1 << 20));
        u16*   w2bT     = (u16*)(ws + ((size_t)77 << 20));
        u16*   inter    = (u16*)(ws + ((size_t)109 << 20));
        float* dbufA    = (float*)(ws + ((size_t)13 << 20));   // 25.2 MB
        float* dbufB    = (float*)(ws + ((size_t)45 << 20));   // 25.2 MB

        router_kernel<<<1, 256, 0, stream>>>(te, tw, slot_tok, slot_w, tok_slot,
                                             tile_e, tile_s, ntiles);
        tcvt8_kernel<<<dim3(H_ / 64, F_ / 64, E_), dim3(8, 32), 0, stream>>>(w2, w2bT);
        gather_x_kernel<<<dim3(MAXT2, 8), 256, 0, stream>>>(x, slot_tok, tile_s, ntiles, xg);
        glu_async_kernel<<<dim3(F_ / 128, MAXT2), 512, 0, stream>>>(
            xg, w1, v1, tile_e, tile_s, ntiles, slot_w, inter);
        down_async_kernel<<<dim3(H_ / 128, MAXT2, 2), 512, 0, stream>>>(
            inter, w2bT, tile_e, tile_s, ntiles, dbufA, dbufB);
        combine_kernel<<<T_, 256, 0, stream>>>(dbufA, dbufB, tok_slot, out);
    } else {
        // ---- fallback: round-3 path (~69 MB, proven) ----
        int*   cnt_g    = (int*)(ws);
        int*   slot_tok = (int*)(ws + (4 << 10));
        float* slot_w   = (float*)(ws + (64 << 10));
        u16*   xb       = (u16*)(ws + ((size_t)1 << 20));
        u16*   w2bT    = (u16*)(ws + ((size_t)5 << 20));
        u16*   inter    = (u16*)(ws + ((size_t)37 << 20));

        hipMemsetAsync(out, 0, (size_t)T_ * H_ * sizeof(float), stream);
        router3_kernel<<<1, 256, 0, stream>>>(te, tw, cnt_g, slot_tok, slot_w);
        cvt_kernel<<<(T_ * H_) / 1024, 256, 0, stream>>>(x, xb);
        tcvt8_kernel<<<dim3(H_ / 64, F_ / 64, E_), dim3(8, 32), 0, stream>>>(w2, w2bT);
        glu3_kernel<<<dim3(E_ * 8, F_ / 128), 256, 0, stream>>>(
            xb, w1, v1, cnt_g, slot_tok, slot_w, inter);
        down3_kernel<<<dim3(E_ * 8, H_ / 128, 2), 256, 0, stream>>>(
            inter, w2bT, cnt_g, slot_tok, out);
    }
}